// Round 1
// baseline (327.004 us; speedup 1.0000x reference)
//
#include <hip/hip_runtime.h>
#include <cstddef>

constexpr int Bsz = 2048;
constexpr int Tsz = 120;
constexpr int Ksz = 128;

// Kernel 0: E[i][j] = exp(transitions[i][j])
__global__ __launch_bounds__(256) void exp_trans_kernel(
    const float* __restrict__ trans, float* __restrict__ E) {
    int i = blockIdx.x * 256 + threadIdx.x;
    if (i < Ksz * Ksz) E[i] = __expf(trans[i]);
}

// Kernel 1: forward recursion + score, one wave per batch element.
__global__ __launch_bounds__(256, 2) void crf_forward_kernel(
    const float* __restrict__ emissions,   // [B,T,K]
    const int* __restrict__ tag_ids,       // [B,T]
    const int* __restrict__ mask,          // [B,T]
    const float* __restrict__ transitions, // [K,K]
    const float* __restrict__ Eexp,        // [K,K] = exp(transitions)
    float* __restrict__ nll)               // [B] out: log_norm - score
{
    __shared__ float Elds[Ksz * Ksz];   // 64 KB
    __shared__ float pbuf[4][Ksz];      // per-wave p broadcast buffer

    const int tid = threadIdx.x;
    // Stage E into LDS, vectorized float4 (16384 floats = 4096 float4).
    {
        const float4* src = (const float4*)Eexp;
        float4* dst = (float4*)Elds;
        #pragma unroll
        for (int k = 0; k < (Ksz * Ksz / 4) / 256; ++k)
            dst[tid + k * 256] = src[tid + k * 256];
    }
    __syncthreads();

    const int wid  = tid >> 6;
    const int lane = tid & 63;
    const int b    = blockIdx.x * 4 + wid;
    const int j0   = 2 * lane;   // this lane owns columns j0, j0+1

    const float* eb = emissions + (size_t)b * Tsz * Ksz;

    float2 a0 = *(const float2*)(eb + j0);
    float alpha0 = a0.x, alpha1 = a0.y;

    for (int t = 1; t < Tsz; ++t) {
        // m = max over all 128 alpha values
        float m = fmaxf(alpha0, alpha1);
        #pragma unroll
        for (int off = 32; off > 0; off >>= 1)
            m = fmaxf(m, __shfl_xor(m, off, 64));

        float p0 = __expf(alpha0 - m);
        float p1 = __expf(alpha1 - m);
        *(float2*)&pbuf[wid][j0] = make_float2(p0, p1);
        // intra-wave LDS write->read: compiler orders via lgkmcnt (same wave)

        float s0 = 0.f, s1 = 0.f;
        #pragma unroll 8
        for (int i = 0; i < Ksz; ++i) {
            float p = pbuf[wid][i];                        // broadcast read
            float2 e = *(const float2*)&Elds[i * Ksz + j0]; // row i, cols j0,j0+1
            s0 = fmaf(p, e.x, s0);
            s1 = fmaf(p, e.y, s1);
        }

        float2 em = *(const float2*)(eb + (size_t)t * Ksz + j0);
        int mt = mask[b * Tsz + t];
        float na0 = m + __logf(s0) + em.x;
        float na1 = m + __logf(s1) + em.y;
        if (mt > 0) { alpha0 = na0; alpha1 = na1; }  // wave-uniform branch
    }

    // log_norm = logsumexp over final alpha
    float m = fmaxf(alpha0, alpha1);
    #pragma unroll
    for (int off = 32; off > 0; off >>= 1)
        m = fmaxf(m, __shfl_xor(m, off, 64));
    float s = __expf(alpha0 - m) + __expf(alpha1 - m);
    #pragma unroll
    for (int off = 32; off > 0; off >>= 1)
        s += __shfl_xor(s, off, 64);
    float log_norm = m + __logf(s);

    // score = unary + binary (gathers; only ~240 loads per batch)
    const int* tb = tag_ids + (size_t)b * Tsz;
    const int* mb = mask + (size_t)b * Tsz;
    float sc = 0.f;
    for (int t = lane; t < Tsz; t += 64) {
        sc += eb[(size_t)t * Ksz + tb[t]] * (float)mb[t];
    }
    for (int t = lane; t < Tsz - 1; t += 64) {
        float pm = (float)mb[t] * (float)mb[t + 1];
        sc += transitions[tb[t] * Ksz + tb[t + 1]] * pm;
    }
    #pragma unroll
    for (int off = 32; off > 0; off >>= 1)
        sc += __shfl_xor(sc, off, 64);

    if (lane == 0) nll[b] = log_norm - sc;
}

// Kernel 2: deterministic fixed-order mean over B values.
__global__ __launch_bounds__(256) void crf_reduce_kernel(
    const float* __restrict__ nll, float* __restrict__ out) {
    __shared__ float buf[256];
    float s = 0.f;
    for (int i = threadIdx.x; i < Bsz; i += 256) s += nll[i];
    buf[threadIdx.x] = s;
    __syncthreads();
    #pragma unroll
    for (int off = 128; off > 0; off >>= 1) {
        if (threadIdx.x < off) buf[threadIdx.x] += buf[threadIdx.x + off];
        __syncthreads();
    }
    if (threadIdx.x == 0) out[0] = buf[0] / (float)Bsz;
}

extern "C" void kernel_launch(void* const* d_in, const int* in_sizes, int n_in,
                              void* d_out, int out_size, void* d_ws, size_t ws_size,
                              hipStream_t stream) {
    const float* emissions   = (const float*)d_in[0];
    const int*   tag_ids     = (const int*)d_in[1];
    const int*   mask        = (const int*)d_in[2];
    const float* transitions = (const float*)d_in[3];
    float* out = (float*)d_out;

    float* Eexp = (float*)d_ws;                       // 64 KB
    float* nll  = (float*)((char*)d_ws + Ksz * Ksz * sizeof(float)); // 8 KB

    exp_trans_kernel<<<(Ksz * Ksz + 255) / 256, 256, 0, stream>>>(transitions, Eexp);
    crf_forward_kernel<<<Bsz / 4, 256, 0, stream>>>(
        emissions, tag_ids, mask, transitions, Eexp, nll);
    crf_reduce_kernel<<<1, 256, 0, stream>>>(nll, out);
}

// Round 2
// 138.455 us; speedup vs baseline: 2.3618x; 2.3618x over previous
//
#include <hip/hip_runtime.h>
#include <cstddef>
#include <cstdint>

typedef __attribute__((ext_vector_type(8))) _Float16 half8;
typedef __attribute__((ext_vector_type(4))) float f32x4;

constexpr int Bsz = 2048, Tsz = 120, Ksz = 128;

// Block = 256 threads = 4 waves, handles 16 batch rows.
// Wave w owns output states [32w, 32w+32) as 2 MFMA row-tiles; E^T fragments
// (exp(transitions) transposed) live in registers for the whole kernel.
// Per step: S^T = E^T · P^T via 8 mfma_f32_16x16x32_f16 (4 k-chunks kept in
// separate accumulators, combined with per-slice-max scales), then
// alpha = m_glob + log(S) + emis, masked. One barrier/step, P double-buffered.
__global__ __launch_bounds__(256) void crf_fwd(
    const float* __restrict__ emis,   // [B,T,K]
    const int* __restrict__ tag,      // [B,T]
    const int* __restrict__ maskg,    // [B,T]
    const float* __restrict__ Tg,     // [K,K]
    float* __restrict__ nll)          // [B]
{
  __shared__ unsigned char Pb[2][16 * 256];   // P as f16 [16 batch][128 states], 16B-slot XOR swizzle
  __shared__ float smaxb[2][4][16];           // per-slice max, per batch col
  __shared__ float sumb[4][16];               // epilogue partial sums
  __shared__ int maskLds[Tsz * 16];           // [t][batch c]

  const int tid = threadIdx.x;
  const int w = tid >> 6, lane = tid & 63;
  const int c = lane & 15, hi = lane >> 4;
  const int b0 = blockIdx.x * 16;

  // Stage masks: LDS[t][c] = mask[b0+c][t]
  for (int i = tid; i < Tsz * 16; i += 256) {
    int cc = i / Tsz, tt = i - cc * Tsz;
    maskLds[tt * 16 + cc] = maskg[(size_t)(b0 + cc) * Tsz + tt];
  }

  // E^T A-fragments: row (out-state j) = 32w+16rti+c, k (in-state i) = 32m+8hi+jj
  half8 Ef[2][4];
  #pragma unroll
  for (int rti = 0; rti < 2; ++rti)
    #pragma unroll
    for (int m = 0; m < 4; ++m) {
      half8 v;
      #pragma unroll
      for (int j = 0; j < 8; ++j) {
        float tv = Tg[(size_t)(32 * m + 8 * hi + j) * Ksz + (32 * w + 16 * rti + c)];
        v[j] = (_Float16)__expf(tv);
      }
      Ef[rti][m] = v;
    }

  const size_t ebase = (size_t)(b0 + c) * Tsz * Ksz;
  const int soff0 = 32 * w + 4 * hi;
  const int soff1 = 32 * w + 16 + 4 * hi;

  // alpha in C-layout: col = batch c, row(state-local) = 4hi + r, tile rti
  f32x4 alpha[2];
  alpha[0] = *(const f32x4*)(emis + ebase + soff0);
  alpha[1] = *(const f32x4*)(emis + ebase + soff1);

  // emissions prefetch, depth 2, named buffers (no runtime-indexed arrays)
  f32x4 pbA0 = *(const f32x4*)(emis + ebase + (size_t)1 * Ksz + soff0);
  f32x4 pbA1 = *(const f32x4*)(emis + ebase + (size_t)1 * Ksz + soff1);
  f32x4 pbB0 = *(const f32x4*)(emis + ebase + (size_t)2 * Ksz + soff0);
  f32x4 pbB1 = *(const f32x4*)(emis + ebase + (size_t)2 * Ksz + soff1);

  // write P (exp(alpha - slice_max)) + slice max into buffer wr
  auto writeP = [&](int wr) {
    float s = fmaxf(fmaxf(fmaxf(alpha[0][0], alpha[0][1]), fmaxf(alpha[0][2], alpha[0][3])),
                    fmaxf(fmaxf(alpha[1][0], alpha[1][1]), fmaxf(alpha[1][2], alpha[1][3])));
    s = fmaxf(s, __shfl_xor(s, 16, 64));
    s = fmaxf(s, __shfl_xor(s, 32, 64));
    #pragma unroll
    for (int rti = 0; rti < 2; ++rti) {
      union { _Float16 h[4]; uint2 u; } pk;
      #pragma unroll
      for (int r = 0; r < 4; ++r) pk.h[r] = (_Float16)__expf(alpha[rti][r] - s);
      int sbyte = (64 * w + 32 * rti + 8 * hi) ^ (c << 4);  // XOR 16B-slot swizzle
      *(uint2*)(&Pb[wr][c * 256 + sbyte]) = pk.u;
    }
    if (lane < 16) smaxb[wr][w][c] = s;
  };

  auto STEP = [&](int t, f32x4& pb0, f32x4& pb1) {
    const int rd = (t - 1) & 1, wr = t & 1;
    half8 bf[4]; float sm[4];
    #pragma unroll
    for (int m = 0; m < 4; ++m) {
      bf[m] = *(const half8*)(&Pb[rd][c * 256 + ((64 * m + 16 * hi) ^ (c << 4))]);
      sm[m] = smaxb[rd][m][c];
    }
    const int mt = maskLds[t * 16 + c];
    float mg = fmaxf(fmaxf(sm[0], sm[1]), fmaxf(sm[2], sm[3]));
    float sw0 = __expf(sm[0] - mg), sw1 = __expf(sm[1] - mg);
    float sw2 = __expf(sm[2] - mg), sw3 = __expf(sm[3] - mg);
    const f32x4 z = {0.f, 0.f, 0.f, 0.f};
    f32x4 acc[2][4];
    #pragma unroll
    for (int rti = 0; rti < 2; ++rti)
      #pragma unroll
      for (int m = 0; m < 4; ++m)
        acc[rti][m] = __builtin_amdgcn_mfma_f32_16x16x32_f16(Ef[rti][m], bf[m], z, 0, 0, 0);
    #pragma unroll
    for (int rti = 0; rti < 2; ++rti) {
      f32x4& pb = rti ? pb1 : pb0;
      #pragma unroll
      for (int r = 0; r < 4; ++r) {
        float S = sw0 * acc[rti][0][r] + sw1 * acc[rti][1][r]
                + sw2 * acc[rti][2][r] + sw3 * acc[rti][3][r];
        float an = mg + __logf(S) + pb[r];
        alpha[rti][r] = (mt > 0) ? an : alpha[rti][r];
      }
    }
    if (t + 2 <= Tsz - 1) {  // prefetch emis[t+2]
      pb0 = *(const f32x4*)(emis + ebase + (size_t)(t + 2) * Ksz + soff0);
      pb1 = *(const f32x4*)(emis + ebase + (size_t)(t + 2) * Ksz + soff1);
    }
    writeP(wr);
    __syncthreads();
  };

  // prologue "step 0": publish P(alpha0) into buffer 0
  writeP(0);
  __syncthreads();

  #pragma unroll 1
  for (int t = 1; t <= Tsz - 3; t += 2) {   // (1,2)...(117,118)
    STEP(t, pbA0, pbA1);
    STEP(t + 1, pbB0, pbB1);
  }
  STEP(Tsz - 1, pbA0, pbA1);                // t = 119

  // final logsumexp over alpha
  float sE = fmaxf(fmaxf(fmaxf(alpha[0][0], alpha[0][1]), fmaxf(alpha[0][2], alpha[0][3])),
                   fmaxf(fmaxf(alpha[1][0], alpha[1][1]), fmaxf(alpha[1][2], alpha[1][3])));
  sE = fmaxf(sE, __shfl_xor(sE, 16, 64));
  sE = fmaxf(sE, __shfl_xor(sE, 32, 64));
  float ps = 0.f;
  #pragma unroll
  for (int rti = 0; rti < 2; ++rti)
    #pragma unroll
    for (int r = 0; r < 4; ++r) ps += __expf(alpha[rti][r] - sE);
  ps += __shfl_xor(ps, 16, 64);
  ps += __shfl_xor(ps, 32, 64);
  if (lane < 16) { smaxb[0][w][c] = sE; sumb[w][c] = ps; }
  __syncthreads();
  float m4 = fmaxf(fmaxf(smaxb[0][0][c], smaxb[0][1][c]), fmaxf(smaxb[0][2][c], smaxb[0][3][c]));
  float ls = __expf(smaxb[0][0][c] - m4) * sumb[0][c]
           + __expf(smaxb[0][1][c] - m4) * sumb[1][c]
           + __expf(smaxb[0][2][c] - m4) * sumb[2][c]
           + __expf(smaxb[0][3][c] - m4) * sumb[3][c];
  const float lognorm = m4 + __logf(ls);   // per lane, for batch c

  // score: wave w handles batches 4w..4w+3; lanes split t
  #pragma unroll 1
  for (int q = 0; q < 4; ++q) {
    const int bb = 4 * w + q;
    const size_t bg = (size_t)(b0 + bb);
    float sc = 0.f;
    {
      const int t1 = lane;  // 0..63 < 120
      int tg0 = tag[bg * Tsz + t1];
      sc += emis[(bg * Tsz + t1) * (size_t)Ksz + tg0] * (float)maskLds[t1 * 16 + bb];
      int tg1 = tag[bg * Tsz + t1 + 1];  // t1+1 <= 64 < 120
      sc += Tg[(size_t)tg0 * Ksz + tg1]
          * (float)(maskLds[t1 * 16 + bb] * maskLds[(t1 + 1) * 16 + bb]);
    }
    {
      const int t2 = lane + 64;
      if (t2 < Tsz) {
        int tg0 = tag[bg * Tsz + t2];
        sc += emis[(bg * Tsz + t2) * (size_t)Ksz + tg0] * (float)maskLds[t2 * 16 + bb];
        if (t2 < Tsz - 1) {
          int tg1 = tag[bg * Tsz + t2 + 1];
          sc += Tg[(size_t)tg0 * Ksz + tg1]
              * (float)(maskLds[t2 * 16 + bb] * maskLds[(t2 + 1) * 16 + bb]);
        }
      }
    }
    #pragma unroll
    for (int off = 32; off; off >>= 1) sc += __shfl_xor(sc, off, 64);
    float ln = __shfl(lognorm, bb, 64);
    if (lane == 0) nll[b0 + bb] = ln - sc;
  }
}

// deterministic fixed-order mean over B values
__global__ __launch_bounds__(256) void crf_reduce(
    const float* __restrict__ nll, float* __restrict__ out) {
  __shared__ float buf[256];
  float s = 0.f;
  for (int i = threadIdx.x; i < Bsz; i += 256) s += nll[i];
  buf[threadIdx.x] = s;
  __syncthreads();
  #pragma unroll
  for (int off = 128; off > 0; off >>= 1) {
    if (threadIdx.x < off) buf[threadIdx.x] += buf[threadIdx.x + off];
    __syncthreads();
  }
  if (threadIdx.x == 0) out[0] = buf[0] / (float)Bsz;
}

extern "C" void kernel_launch(void* const* d_in, const int* in_sizes, int n_in,
                              void* d_out, int out_size, void* d_ws, size_t ws_size,
                              hipStream_t stream) {
  const float* emissions   = (const float*)d_in[0];
  const int*   tag_ids     = (const int*)d_in[1];
  const int*   mask        = (const int*)d_in[2];
  const float* transitions = (const float*)d_in[3];

  float* nll = (float*)d_ws;  // 2048 floats

  crf_fwd<<<Bsz / 16, 256, 0, stream>>>(emissions, tag_ids, mask, transitions, nll);
  crf_reduce<<<1, 256, 0, stream>>>(nll, (float*)d_out);
}

// Round 3
// 128.707 us; speedup vs baseline: 2.5407x; 1.0757x over previous
//
#include <hip/hip_runtime.h>
#include <cstddef>
#include <cstdint>

typedef __attribute__((ext_vector_type(8))) _Float16 half8;
typedef __attribute__((ext_vector_type(4))) float f32x4;

constexpr int Bsz = 2048, Tsz = 120, Ksz = 128;
constexpr int BPB = 8;   // batches per block -> 256 blocks (1 per CU)

// Raw barrier: drain LDS (P-writes visible) but leave global prefetch loads
// in flight across the barrier (no vmcnt(0) drain -- the round-2 stall).
#define BAR() do { asm volatile("s_waitcnt lgkmcnt(0)" ::: "memory"); \
                   __builtin_amdgcn_s_barrier();                      \
                   asm volatile("" ::: "memory"); } while (0)

__global__ __launch_bounds__(256) void crf_fwd(
    const float* __restrict__ emis,   // [B,T,K]
    const int* __restrict__ tag,      // [B,T]
    const int* __restrict__ maskg,    // [B,T]
    const float* __restrict__ Tg,     // [K,K]
    float* __restrict__ nll)          // [B]
{
  __shared__ float Tst[Ksz * Ksz];                      // 64 KB staging for transitions
  __shared__ __align__(16) unsigned char Pb[2][16 * 256]; // P f16, XOR 16B-slot swizzle
  __shared__ __align__(16) float smx[2][16][4];         // [buf][batch c][wave] slice max
  __shared__ float esm[4][16], esum[4][16];             // epilogue
  __shared__ int maskLds[Tsz * BPB];

  const int tid = threadIdx.x;
  const int w = tid >> 6, lane = tid & 63;
  const int c = lane & 15, hi = lane >> 4;
  const int b0 = blockIdx.x * BPB;
  const int bc = c & (BPB - 1);          // cols 8..15 duplicate batches 0..7

  // Coalesced stage of transitions, and masks
  {
    const f32x4* src = (const f32x4*)Tg;
    f32x4* dst = (f32x4*)Tst;
    #pragma unroll
    for (int k = 0; k < (Ksz * Ksz / 4) / 256; ++k)
      dst[tid + k * 256] = src[tid + k * 256];
  }
  for (int i = tid; i < Tsz * BPB; i += 256) {
    int bb = i / Tsz, tt = i - bb * Tsz;
    maskLds[tt * BPB + bb] = maskg[(size_t)(b0 + bb) * Tsz + tt];
  }
  __syncthreads();

  // E^T A-fragments in registers: row(out j)=32w+16rti+c, k(in i)=32m+8hi+jj
  half8 Ef[2][4];
  #pragma unroll
  for (int rti = 0; rti < 2; ++rti)
    #pragma unroll
    for (int m = 0; m < 4; ++m) {
      half8 v;
      #pragma unroll
      for (int j = 0; j < 8; ++j)
        v[j] = (_Float16)__expf(Tst[(32 * m + 8 * hi + j) * Ksz + (32 * w + 16 * rti + c)]);
      Ef[rti][m] = v;
    }

  const size_t ebase = (size_t)(b0 + bc) * Tsz * Ksz;
  const int soff0 = 32 * w + 4 * hi, soff1 = soff0 + 16;

  f32x4 alpha[2];
  alpha[0] = *(const f32x4*)(emis + ebase + soff0);
  alpha[1] = *(const f32x4*)(emis + ebase + soff1);

  // emissions prefetch, depth 2, named regs
  f32x4 pbA0 = *(const f32x4*)(emis + ebase + (size_t)1 * Ksz + soff0);
  f32x4 pbA1 = *(const f32x4*)(emis + ebase + (size_t)1 * Ksz + soff1);
  f32x4 pbB0 = *(const f32x4*)(emis + ebase + (size_t)2 * Ksz + soff0);
  f32x4 pbB1 = *(const f32x4*)(emis + ebase + (size_t)2 * Ksz + soff1);

  auto writeP = [&](int wr) {
    float s = fmaxf(fmaxf(fmaxf(alpha[0][0], alpha[0][1]), fmaxf(alpha[0][2], alpha[0][3])),
                    fmaxf(fmaxf(alpha[1][0], alpha[1][1]), fmaxf(alpha[1][2], alpha[1][3])));
    s = fmaxf(s, __shfl_xor(s, 16, 64));
    s = fmaxf(s, __shfl_xor(s, 32, 64));
    #pragma unroll
    for (int rti = 0; rti < 2; ++rti) {
      union { _Float16 h[4]; uint2 u; } pk;
      #pragma unroll
      for (int r = 0; r < 4; ++r) pk.h[r] = (_Float16)__expf(alpha[rti][r] - s);
      int sbyte = (64 * w + 32 * rti + 8 * hi) ^ (c << 4);
      *(uint2*)(&Pb[wr][c * 256 + sbyte]) = pk.u;
    }
    if (lane < 16) smx[wr][lane][w] = s;
  };

  auto STEP = [&](int t, f32x4& pb0, f32x4& pb1) {
    const int rd = (t - 1) & 1, wr = t & 1;
    // LDS reads issued first
    half8 bf[4];
    #pragma unroll
    for (int m = 0; m < 4; ++m)
      bf[m] = *(const half8*)(&Pb[rd][c * 256 + ((64 * m + 16 * hi) ^ (c << 4))]);
    const f32x4 smv = *(const f32x4*)(&smx[rd][c][0]);
    const int mt = maskLds[t * BPB + bc];
    const float mg = fmaxf(fmaxf(smv[0], smv[1]), fmaxf(smv[2], smv[3]));
    // consume prefetched emis into base, then immediately refill (t+2)
    f32x4 base0, base1;
    #pragma unroll
    for (int r = 0; r < 4; ++r) { base0[r] = mg + pb0[r]; base1[r] = mg + pb1[r]; }
    if (t + 2 <= Tsz - 1) {
      pb0 = *(const f32x4*)(emis + ebase + (size_t)(t + 2) * Ksz + soff0);
      pb1 = *(const f32x4*)(emis + ebase + (size_t)(t + 2) * Ksz + soff1);
    }
    const float sw0 = __expf(smv[0] - mg), sw1 = __expf(smv[1] - mg);
    const float sw2 = __expf(smv[2] - mg), sw3 = __expf(smv[3] - mg);
    const f32x4 z = {0.f, 0.f, 0.f, 0.f};
    f32x4 acc[2][4];
    #pragma unroll
    for (int rti = 0; rti < 2; ++rti)
      #pragma unroll
      for (int m = 0; m < 4; ++m)
        acc[rti][m] = __builtin_amdgcn_mfma_f32_16x16x32_f16(Ef[rti][m], bf[m], z, 0, 0, 0);
    #pragma unroll
    for (int rti = 0; rti < 2; ++rti) {
      const f32x4& bse = rti ? base1 : base0;
      #pragma unroll
      for (int r = 0; r < 4; ++r) {
        float S = sw0 * acc[rti][0][r] + sw1 * acc[rti][1][r]
                + sw2 * acc[rti][2][r] + sw3 * acc[rti][3][r];
        float na = bse[r] + __logf(S);
        alpha[rti][r] = (mt > 0) ? na : alpha[rti][r];
      }
    }
    if (t != Tsz - 1) { writeP(wr); BAR(); }   // last step: no publish needed
  };

  writeP(0);
  BAR();

  #pragma unroll 1
  for (int t = 1; t <= Tsz - 3; t += 2) {   // (1,2)...(117,118)
    STEP(t, pbA0, pbA1);
    STEP(t + 1, pbB0, pbB1);
  }
  STEP(Tsz - 1, pbA0, pbA1);                // t = 119

  // final logsumexp over alpha
  float sE = fmaxf(fmaxf(fmaxf(alpha[0][0], alpha[0][1]), fmaxf(alpha[0][2], alpha[0][3])),
                   fmaxf(fmaxf(alpha[1][0], alpha[1][1]), fmaxf(alpha[1][2], alpha[1][3])));
  sE = fmaxf(sE, __shfl_xor(sE, 16, 64));
  sE = fmaxf(sE, __shfl_xor(sE, 32, 64));
  float ps = 0.f;
  #pragma unroll
  for (int rti = 0; rti < 2; ++rti)
    #pragma unroll
    for (int r = 0; r < 4; ++r) ps += __expf(alpha[rti][r] - sE);
  ps += __shfl_xor(ps, 16, 64);
  ps += __shfl_xor(ps, 32, 64);
  if (lane < 16) { esm[w][lane] = sE; esum[w][lane] = ps; }
  __syncthreads();
  float m4 = fmaxf(fmaxf(esm[0][c], esm[1][c]), fmaxf(esm[2][c], esm[3][c]));
  float ls = __expf(esm[0][c] - m4) * esum[0][c]
           + __expf(esm[1][c] - m4) * esum[1][c]
           + __expf(esm[2][c] - m4) * esum[2][c]
           + __expf(esm[3][c] - m4) * esum[3][c];
  const float lognorm = m4 + __logf(ls);   // valid for batch col c (c<8 real)

  // score: wave w handles batches 2w, 2w+1; lanes split t
  #pragma unroll 1
  for (int q = 0; q < 2; ++q) {
    const int bb = 2 * w + q;
    const size_t bg = (size_t)(b0 + bb);
    float sc = 0.f;
    {
      const int t1 = lane;  // < 120
      int tg0 = tag[bg * Tsz + t1];
      sc += emis[(bg * Tsz + t1) * (size_t)Ksz + tg0] * (float)maskLds[t1 * BPB + bb];
      int tg1 = tag[bg * Tsz + t1 + 1];   // t1+1 <= 64 < 120
      sc += Tg[(size_t)tg0 * Ksz + tg1]
          * (float)(maskLds[t1 * BPB + bb] * maskLds[(t1 + 1) * BPB + bb]);
    }
    {
      const int t2 = lane + 64;
      if (t2 < Tsz) {
        int tg0 = tag[bg * Tsz + t2];
        sc += emis[(bg * Tsz + t2) * (size_t)Ksz + tg0] * (float)maskLds[t2 * BPB + bb];
        if (t2 < Tsz - 1) {
          int tg1 = tag[bg * Tsz + t2 + 1];
          sc += Tg[(size_t)tg0 * Ksz + tg1]
              * (float)(maskLds[t2 * BPB + bb] * maskLds[(t2 + 1) * BPB + bb]);
        }
      }
    }
    #pragma unroll
    for (int off = 32; off; off >>= 1) sc += __shfl_xor(sc, off, 64);
    float ln = __shfl(lognorm, bb, 64);
    if (lane == 0) nll[b0 + bb] = ln - sc;
  }
}

// deterministic fixed-order mean over B values
__global__ __launch_bounds__(256) void crf_reduce(
    const float* __restrict__ nll, float* __restrict__ out) {
  __shared__ float buf[256];
  float s = 0.f;
  for (int i = threadIdx.x; i < Bsz; i += 256) s += nll[i];
  buf[threadIdx.x] = s;
  __syncthreads();
  #pragma unroll
  for (int off = 128; off > 0; off >>= 1) {
    if (threadIdx.x < off) buf[threadIdx.x] += buf[threadIdx.x + off];
    __syncthreads();
  }
  if (threadIdx.x == 0) out[0] = buf[0] / (float)Bsz;
}

extern "C" void kernel_launch(void* const* d_in, const int* in_sizes, int n_in,
                              void* d_out, int out_size, void* d_ws, size_t ws_size,
                              hipStream_t stream) {
  const float* emissions   = (const float*)d_in[0];
  const int*   tag_ids     = (const int*)d_in[1];
  const int*   mask        = (const int*)d_in[2];
  const float* transitions = (const float*)d_in[3];

  float* nll = (float*)d_ws;  // 2048 floats

  crf_fwd<<<Bsz / BPB, 256, 0, stream>>>(emissions, tag_ids, mask, transitions, nll);
  crf_reduce<<<1, 256, 0, stream>>>(nll, (float*)d_out);
}